// Round 2
// baseline (438.836 us; speedup 1.0000x reference)
//
#include <hip/hip_runtime.h>

// Fold (col2im): x (8, 32, 8, 8, 4096) f32, kernel (8,8), stride (4,4),
// patch grid 64x64 -> out (8, 32, 260, 260) f32.
//
// Gather formulation, vectorized for 1 KB-contiguous wave loads:
//   out[bc, h=4*ip+r, w=4j+dj'] sums
//     x[bc, r,   dj, ip,   j]   (dj = dj',   lo kernel row, valid ip<=63)
//   + x[bc, r+4, dj, ip-1, j]   (hi kernel row, valid ip>=1)
//   with dj' = dj for dj<4 at j=t, and dj' = dj-4 for dj>=4 at j=t-1.
//
// Lane layout: lane l = (io, q), io = l>>4, q = l&15. ip = 4*g + io.
// Per plane, lane loads float4 at element ip*64 + 4q = 256g + 4*l ->
// the 64 lanes of a wave read 1024 contiguous bytes per load instruction
// (vs 256 B scattered scalar bursts in the previous version). The j-1
// element needed by hi-dj planes comes from the neighbor lane via
// __shfl_up (no extra bytes). Each lane emits 16 contiguous outputs
// (w = 16q .. 16q+15) as 4 aligned float4 stores; lane q==15 also emits
// the 4-wide row tail (w = 256..259, which only has hi-dj contributions).
//
// HBM traffic is unchanged and minimal: read x once (268 MB), write out
// once (69 MB). VMEM instructions per output drop 4x; burst size rises 4x.

#define L      4096
#define NP     64
#define H_OUT  260

typedef float vfloat4 __attribute__((ext_vector_type(4)));

__device__ __forceinline__ float elem(const vfloat4& v, int e) {
    return v[e];
}

__global__ __launch_bounds__(256) void fold_kernel(const float* __restrict__ x,
                                                   float* __restrict__ out) {
    int tid  = blockIdx.x * 256 + threadIdx.x;
    int lane = tid & 63;
    int wave = tid >> 6;

    // wave -> (bc, r, g): 17 ip-quads cover ip = 0..64 (ip<=64 valid)
    int g    = wave % 17;
    int rest = wave / 17;
    int r    = rest & 3;          // h residue: h = 4*ip + r
    int bc   = rest >> 2;         // 0..255

    int q  = lane & 15;           // j-quad: j = 4q .. 4q+3
    int io = lane >> 4;           // 0..3
    int ip = 4 * g + io;          // 0..67; rows with ip > 64 are idle

    bool va = (ip < NP);                  // lo row (di = r) uses patch row ip
    bool vb = (ip >= 1) && (ip <= NP);    // hi row (di = r+4) uses patch row ip-1

    int xb   = bc * (64 * L);
    int aoff = xb + r       * (8 * L) + ip       * NP + 4 * q;
    int boff = xb + (r + 4) * (8 * L) + (ip - 1) * NP + 4 * q;

    const vfloat4 z4 = (vfloat4){0.f, 0.f, 0.f, 0.f};
    vfloat4 A[8], B[8];
    #pragma unroll
    for (int dj = 0; dj < 8; ++dj) {
        A[dj] = va ? *reinterpret_cast<const vfloat4*>(x + aoff + dj * L) : z4;
        B[dj] = vb ? *reinterpret_cast<const vfloat4*>(x + boff + dj * L) : z4;
    }

    // j = 4q-1 element of each hi-dj plane lives in lane l-1 (element 3).
    float sa[4], sb[4];
    #pragma unroll
    for (int s = 0; s < 4; ++s) {
        float ta = __shfl_up(A[4 + s][3], 1);
        float tb = __shfl_up(B[4 + s][3], 1);
        sa[s] = (q == 0) ? 0.f : ta;   // q==0, e==0 -> j=-1: no contribution
        sb[s] = (q == 0) ? 0.f : tb;
    }

    if (ip <= NP) {
        int h  = 4 * ip + r;                               // 0..259
        int ob = (bc * H_OUT + h) * H_OUT + 16 * q;        // 16B-aligned

        #pragma unroll
        for (int e = 0; e < 4; ++e) {                      // j = 4q + e
            vfloat4 v;
            #pragma unroll
            for (int s = 0; s < 4; ++s) {                  // w = 16q + 4e + s
                float lo = elem(A[s], e) + elem(B[s], e);
                float hi_a = (e == 0) ? sa[s] : elem(A[4 + s], e - 1);
                float hi_b = (e == 0) ? sb[s] : elem(B[4 + s], e - 1);
                v[s] = lo + (hi_a + hi_b);
            }
            __builtin_nontemporal_store(v, reinterpret_cast<vfloat4*>(out + ob + 4 * e));
        }

        if (q == 15) {
            // Row tail w = 256..259: only dj = s+4 at j = 63 contributes.
            vfloat4 v = (vfloat4){A[4][3] + B[4][3],
                                  A[5][3] + B[5][3],
                                  A[6][3] + B[6][3],
                                  A[7][3] + B[7][3]};
            __builtin_nontemporal_store(v, reinterpret_cast<vfloat4*>(out + ob + 16));
        }
    }
}

extern "C" void kernel_launch(void* const* d_in, const int* in_sizes, int n_in,
                              void* d_out, int out_size, void* d_ws, size_t ws_size,
                              hipStream_t stream) {
    const float* x = (const float*)d_in[0];
    float* out     = (float*)d_out;

    // waves = 256 bc * 4 r * 17 g = 17408; 4 waves per 256-thread block.
    const int grid  = 17408 / 4;   // 4352
    const int block = 256;

    fold_kernel<<<grid, block, 0, stream>>>(x, out);
}

// Round 3
// 384.953 us; speedup vs baseline: 1.1400x; 1.1400x over previous
//
#include <hip/hip_runtime.h>

// Fold (col2im): x (8, 32, 8, 8, 4096) f32, kernel (8,8), stride (4,4),
// patch grid 64x64 -> out (8, 32, 260, 260) f32.
//
// Gather formulation, vectorized for 1 KB-contiguous wave loads:
//   out[bc, h=4*ip+r, w=4j+dj'] sums
//     x[bc, r,   dj, ip,   j]   (lo kernel row, valid ip<=63)
//   + x[bc, r+4, dj, ip-1, j]   (hi kernel row, valid ip>=1)
//
// Lane layout: lane l = (io, q), io = l>>4, q = l&15. ip = 4*g + io.
// Per plane, lane loads float4 at element ip*64 + 4q = 256g + 4*l ->
// the 64 lanes of a wave read 1024 contiguous bytes per load instruction.
// The j-1 element needed by hi-dj planes comes from the neighbor lane via
// __shfl_up (no extra bytes). Each lane emits 16 contiguous outputs
// (w = 16q .. 16q+15) as 4 aligned float4 stores (64 B contiguous per
// lane, 1 KB per io group); lane q==15 also emits the 4-wide row tail.
//
// Round-2 lesson (rocprof): nontemporal stores bypassed L2 and wrote
// uncombined partial sectors to HBM -> WRITE_SIZE 165.6 MB vs 69.4 MB
// ideal (2.4x amplification), write-bound at 0.93 TB/s effective.
// Plain stores let L2 write-combine full 64 B lines.

#define L      4096
#define NP     64
#define H_OUT  260

typedef float vfloat4 __attribute__((ext_vector_type(4)));

__device__ __forceinline__ float elem(const vfloat4& v, int e) {
    return v[e];
}

__global__ __launch_bounds__(256) void fold_kernel(const float* __restrict__ x,
                                                   float* __restrict__ out) {
    int tid  = blockIdx.x * 256 + threadIdx.x;
    int lane = tid & 63;
    int wave = tid >> 6;

    // wave -> (bc, r, g): 17 ip-quads cover ip = 0..64 (ip<=64 valid)
    int g    = wave % 17;
    int rest = wave / 17;
    int r    = rest & 3;          // h residue: h = 4*ip + r
    int bc   = rest >> 2;         // 0..255

    int q  = lane & 15;           // j-quad: j = 4q .. 4q+3
    int io = lane >> 4;           // 0..3
    int ip = 4 * g + io;          // 0..67; rows with ip > 64 are idle

    bool va = (ip < NP);                  // lo row (di = r) uses patch row ip
    bool vb = (ip >= 1) && (ip <= NP);    // hi row (di = r+4) uses patch row ip-1

    int xb   = bc * (64 * L);
    int aoff = xb + r       * (8 * L) + ip       * NP + 4 * q;
    int boff = xb + (r + 4) * (8 * L) + (ip - 1) * NP + 4 * q;

    const vfloat4 z4 = (vfloat4){0.f, 0.f, 0.f, 0.f};
    vfloat4 A[8], B[8];
    #pragma unroll
    for (int dj = 0; dj < 8; ++dj) {
        A[dj] = va ? *reinterpret_cast<const vfloat4*>(x + aoff + dj * L) : z4;
        B[dj] = vb ? *reinterpret_cast<const vfloat4*>(x + boff + dj * L) : z4;
    }

    // j = 4q-1 element of each hi-dj plane lives in lane l-1 (element 3).
    float sa[4], sb[4];
    #pragma unroll
    for (int s = 0; s < 4; ++s) {
        float ta = __shfl_up(A[4 + s][3], 1);
        float tb = __shfl_up(B[4 + s][3], 1);
        sa[s] = (q == 0) ? 0.f : ta;   // q==0, e==0 -> j=-1: no contribution
        sb[s] = (q == 0) ? 0.f : tb;
    }

    if (ip <= NP) {
        int h  = 4 * ip + r;                               // 0..259
        int ob = (bc * H_OUT + h) * H_OUT + 16 * q;        // 16B-aligned

        #pragma unroll
        for (int e = 0; e < 4; ++e) {                      // j = 4q + e
            vfloat4 v;
            #pragma unroll
            for (int s = 0; s < 4; ++s) {                  // w = 16q + 4e + s
                float lo = elem(A[s], e) + elem(B[s], e);
                float hi_a = (e == 0) ? sa[s] : elem(A[4 + s], e - 1);
                float hi_b = (e == 0) ? sb[s] : elem(B[4 + s], e - 1);
                v[s] = lo + (hi_a + hi_b);
            }
            *reinterpret_cast<vfloat4*>(out + ob + 4 * e) = v;
        }

        if (q == 15) {
            // Row tail w = 256..259: only dj = s+4 at j = 63 contributes.
            vfloat4 v = (vfloat4){A[4][3] + B[4][3],
                                  A[5][3] + B[5][3],
                                  A[6][3] + B[6][3],
                                  A[7][3] + B[7][3]};
            *reinterpret_cast<vfloat4*>(out + ob + 16) = v;
        }
    }
}

extern "C" void kernel_launch(void* const* d_in, const int* in_sizes, int n_in,
                              void* d_out, int out_size, void* d_ws, size_t ws_size,
                              hipStream_t stream) {
    const float* x = (const float*)d_in[0];
    float* out     = (float*)d_out;

    // waves = 256 bc * 4 r * 17 g = 17408; 4 waves per 256-thread block.
    const int grid  = 17408 / 4;   // 4352
    const int block = 256;

    fold_kernel<<<grid, block, 0, stream>>>(x, out);
}

// Round 4
// 369.704 us; speedup vs baseline: 1.1870x; 1.0412x over previous
//
#include <hip/hip_runtime.h>

// Fold (col2im): x (8, 32, 8, 8, 4096) f32, kernel (8,8), stride (4,4),
// patch grid 64x64 -> out (8, 32, 260, 260) f32.
//
// Round-3 analysis: gather kernel reached ~128 us but only ~1.6 TB/s vs the
// 6.5 TB/s the chip does on contiguous fills. Remaining suspect: each wave's
// 16 concurrent 1 KB read bursts sit at exact power-of-2 strides (16 KB /
// 128 KB / 1 MB) -> DRAM channel+bank aliasing, short scattered bursts.
//
// This version: block-level LDS staging. Block (bc, r, G) stages 16 plane
// chunks of 4 KB CONTIGUOUS each (16 rows x 256 B) into 64 KB LDS via
// global_load_lds (linear LDS dest, 1 KB per wave-instruction, 4 back-to-back
// instructions per chunk -> 32 consecutive cache lines). Grid order (G
// fastest, then r, then bc) makes consecutive blocks read consecutive 4 KB
// chunks: the grid walks x nearly sequentially, like a fill/copy kernel.
//
// Math per output row h = 4*ip + r (r = h&3), w = 4u + s (s = w&3):
//   out[bc,h,w] = A[s][ip][u]        (di=r,   dj=s,   valid u<=63, ip<=63)
//               + B[s][ip-1][u]      (di=r+4, dj=s,   valid ip>=1)
//               + A[s+4][ip][u-1]    (di=r,   dj=s+4, valid u>=1)
//               + B[s+4][ip-1][u-1]  (di=r+4, dj=s+4, valid ip>=1, u>=1)
// where A[p] = x[bc, r, p, :, :], B[p] = x[bc, r+4, p, :, :].
//
// LDS: A chunks = rows 16G..16G+15 of A[p]; B chunks = rows 16G-1..16G+14 of
// B[p] (slot ii holds row ip-1 for ip = 16G+ii). For G=0 slot 0 holds the
// preceding plane's last row (always in-bounds globally since di>=4) and is
// masked to zero in compute (ip>=1 predicate). Row ip=64 (h=256+r, hi kernel
// row only) is handled by G==3 blocks with 8 tiny direct global reads.
//
// HBM bytes unchanged and minimal: read x once (268 MB), write out once
// (69 MB). Only the ACCESS PATTERN changes: all read streams >= 4 KB
// sequential, grid-order globally sequential.

#define L      4096
#define NP     64
#define H_OUT  260

typedef float vfloat4 __attribute__((ext_vector_type(4)));

__global__ __launch_bounds__(256) void fold_kernel(const float* __restrict__ x,
                                                   float* __restrict__ out) {
    __shared__ float lds[16384];   // 64 KB: chunk c at lds[c*1024], c=0..15
                                   // c<8: A plane p=c; c>=8: B plane p=c-8

    int bid = blockIdx.x;
    int G   = bid & 3;             // ip-quadrant, fastest -> sequential x walk
    int r   = (bid >> 2) & 3;      // h residue
    int bc  = bid >> 4;            // 0..255

    int lane = threadIdx.x & 63;
    int wv   = threadIdx.x >> 6;   // wave 0..3

    // ---- stage: 16 chunks x 4 KB contiguous, 4 chunks per wave ----
    #pragma unroll
    for (int ci = 0; ci < 4; ++ci) {
        int c   = 4 * wv + ci;     // 0..15
        int isB = c >> 3;          // 0: A (di=r), 1: B (di=r+4)
        int p   = c & 7;           // dj plane
        int di  = r + 4 * isB;
        // B chunk starts one row earlier (16G-1); always in-bounds since
        // di>=4 => at least 32 planes precede it within this bc.
        long gb = ((long)(bc * 64 + di * 8 + p)) * L + (long)(16 * G - isB) * 64;
        const float* gp = x + gb + lane * 4;
        float* lp = lds + c * 1024;
        #pragma unroll
        for (int k = 0; k < 4; ++k) {
            __builtin_amdgcn_global_load_lds(
                (const __attribute__((address_space(1))) void*)(gp + k * 256),
                (__attribute__((address_space(3))) void*)(lp + k * 256),
                16, 0, 0);
        }
    }
    __syncthreads();

    // ---- compute: thread t -> output row ii (ip=16G+ii), w-block ug ----
    int t  = threadIdx.x;
    int ii = t >> 4;               // 0..15
    int ug = t & 15;               // w = 16*ug .. 16*ug+15
    int ip = 16 * G + ii;          // 0..63
    bool bvalid = (ip >= 1);

    const vfloat4* l4 = (const vfloat4*)lds;
    const vfloat4 vz = {0.f, 0.f, 0.f, 0.f};

    vfloat4 o[4];                  // o[e][s] -> w = 16ug + 4e + s
    float tl[4];                   // row tail w = 256+s (ug==15 only)

    #pragma unroll
    for (int s = 0; s < 4; ++s) {
        int ai = s * 256 + ii * 16 + ug;          // A[s]
        int bi = 2048 + ai;                       // B[s]
        int ahi = (s + 4) * 256 + ii * 16 + ug;   // A[s+4]
        int bhi = 2048 + ahi;                     // B[s+4]

        vfloat4 alo = l4[ai];
        vfloat4 blo = bvalid ? l4[bi] : vz;
        vfloat4 ahc = l4[ahi];
        vfloat4 bhc = bvalid ? l4[bhi] : vz;
        float ahp = (ug > 0) ? l4[ahi - 1][3] : 0.f;             // u = 16ug-1
        float bhp = (ug > 0 && bvalid) ? l4[bhi - 1][3] : 0.f;

        o[0][s] = alo[0] + blo[0] + ahp    + bhp;
        o[1][s] = alo[1] + blo[1] + ahc[0] + bhc[0];
        o[2][s] = alo[2] + blo[2] + ahc[1] + bhc[1];
        o[3][s] = alo[3] + blo[3] + ahc[2] + bhc[2];
        tl[s]   = ahc[3] + bhc[3];                // u-1 = 63 contribution
    }

    long orow = ((long)(bc * H_OUT) + (4 * ip + r)) * H_OUT;  // multiple of 4
    vfloat4* op = (vfloat4*)(out + orow);
    op[4 * ug + 0] = o[0];
    op[4 * ug + 1] = o[1];
    op[4 * ug + 2] = o[2];
    op[4 * ug + 3] = o[3];
    if (ug == 15) {
        vfloat4 tv = {tl[0], tl[1], tl[2], tl[3]};
        op[64] = tv;               // w = 256..259
    }

    // ---- extra row ip=64 (h = 256+r): hi kernel row only, G==3 blocks ----
    if (G == 3 && t < 65) {
        int u = t;                 // w = 4u + s
        const float* pb = x + ((long)(bc * 64 + (r + 4) * 8)) * L + 63 * 64;
        vfloat4 v;
        #pragma unroll
        for (int s = 0; s < 4; ++s) {
            float lo = (u <= 63) ? pb[(long)s * L + u] : 0.f;
            float hi = (u >= 1) ? pb[(long)(s + 4) * L + u - 1] : 0.f;
            v[s] = lo + hi;
        }
        ((vfloat4*)(out + ((long)(bc * H_OUT) + 256 + r) * H_OUT))[u] = v;
    }
}

extern "C" void kernel_launch(void* const* d_in, const int* in_sizes, int n_in,
                              void* d_out, int out_size, void* d_ws, size_t ws_size,
                              hipStream_t stream) {
    const float* x = (const float*)d_in[0];
    float* out     = (float*)d_out;

    // blocks = 256 bc * 4 r * 4 G = 4096, 256 threads, 64 KB LDS each.
    fold_kernel<<<4096, 256, 0, stream>>>(x, out);
}

// Round 5
// 363.112 us; speedup vs baseline: 1.2085x; 1.0182x over previous
//
#include <hip/hip_runtime.h>

// Fold (col2im): x (8, 32, 8, 8, 4096) f32, kernel (8,8), stride (4,4),
// patch grid 64x64 -> out (8, 32, 260, 260) f32.
//
// Round-4 lesson: sequential-read LDS staging with 64 KB/block gained only
// ~15 us -> read pattern was not the main limiter. New theory: the
// stage->sync->compute serialization with only 2 resident blocks/CU (64 KB
// LDS each) leaves the memory pipe half-idle (per-CU bytes predict ~52 us,
// observed ~113 us). This version halves the tile: 8 output rows/block,
// 16 chunks x 2 KB = 32 KB LDS -> 5 resident blocks/CU, 20 waves/CU, so
// staging of one block overlaps compute of four others.
//
// Math per output row h = 4*ip + r (r = h&3), w = 4k + s (s = w&3), output
// float4 index k = 0..64:
//   out[bc,h,4k+s] = A[s][ip][k]      (di=r,   dj=s,   valid k<=63, ip<=63)
//                  + B[s][ip-1][k]    (di=r+4, dj=s,   valid ip>=1)
//                  + A[s+4][ip][k-1]  (di=r,   dj=s+4, valid k>=1)
//                  + B[s+4][ip-1][k-1]
// where A[p] = x[bc, r, p, :, :], B[p] = x[bc, r+4, p, :, :] (64x64 planes).
//
// Block (bc, r, H): rows ip = 8H..8H+7. LDS chunk c (2 KB, c=0..15):
//   c = p   : rows 8H..8H+7   of A[p]
//   c = 8+p : rows 8H-1..8H+6 of B[p]  (slot ii holds row ip-1)
// B chunk for H=0 starts at the previous plane's row 63 (globally in-bounds
// since di=r+4>=4) and is masked by the ip>=1 predicate in compute.
// Row ip=64 (h=256+r, hi kernel row only) handled by H==7 blocks directly.
//
// Thread t: ii = t>>5 (row), ug = t&31 -> output float4s k = 2ug, 2ug+1
// (+ tail k=64 when ug==31). All vector element indices are compile-time;
// the even/odd-k variation is handled with scalar selects (no scratch).

#define L      4096
#define NP     64
#define H_OUT  260

typedef float vfloat4 __attribute__((ext_vector_type(4)));

__global__ __launch_bounds__(256) void fold_kernel(const float* __restrict__ x,
                                                   float* __restrict__ out) {
    __shared__ float lds[8192];    // 32 KB: chunk c at lds[c*512]

    int bid = blockIdx.x;
    int H   = bid & 7;             // ip-octant, fastest -> sequential x walk
    int r   = (bid >> 3) & 3;      // h residue
    int bc  = bid >> 5;            // 0..255

    int lane = threadIdx.x & 63;
    int wv   = threadIdx.x >> 6;   // wave 0..3

    // ---- stage: 16 chunks x 2 KB contiguous, 4 chunks per wave ----
    #pragma unroll
    for (int ci = 0; ci < 4; ++ci) {
        int c   = 4 * wv + ci;     // 0..15
        int isB = c >> 3;          // 0: A (di=r), 1: B (di=r+4)
        int p   = c & 7;           // dj plane
        int di  = r + 4 * isB;
        long gb = ((long)(bc * 64 + di * 8 + p)) * L + (long)(8 * H - isB) * 64;
        const float* gp = x + gb + lane * 4;
        float* lp = lds + c * 512;
        #pragma unroll
        for (int k = 0; k < 2; ++k) {
            __builtin_amdgcn_global_load_lds(
                (const __attribute__((address_space(1))) void*)(gp + k * 256),
                (__attribute__((address_space(3))) void*)(lp + k * 256),
                16, 0, 0);
        }
    }
    __syncthreads();

    // ---- compute ----
    int t   = threadIdx.x;
    int ii  = t >> 5;              // 0..7
    int ug  = t & 31;              // k = 2ug, 2ug+1
    int ip  = 8 * H + ii;          // 0..63
    bool bvalid = (ip >= 1);
    bool odd    = (ug & 1);
    int  f      = ug >> 1;         // input float4 index 0..15

    const vfloat4* l4 = (const vfloat4*)lds;
    const vfloat4 vz = {0.f, 0.f, 0.f, 0.f};

    vfloat4 o0, o1, tl;
    #pragma unroll
    for (int s = 0; s < 4; ++s) {
        int ai  = s * 128 + ii * 16 + f;          // A[s]
        int bi  = 1024 + ai;                      // B[s]
        int ahi = (s + 4) * 128 + ii * 16 + f;    // A[s+4]
        int bhi = 1024 + ahi;                     // B[s+4]

        vfloat4 alo = l4[ai];
        vfloat4 blo = bvalid ? l4[bi] : vz;
        vfloat4 ahc = l4[ahi];
        vfloat4 bhc = bvalid ? l4[bhi] : vz;
        // prev float4's last element (u = 2ug-1 for even k path)
        float ap3 = (!odd && ug > 0) ? l4[ahi - 1][3] : 0.f;
        float bp3 = (!odd && ug > 0 && bvalid) ? l4[bhi - 1][3] : 0.f;

        // k = 2ug: lo elem e0 = odd?2:0 ; hi u=k-1: odd ? ahc[1] : prev[3]
        float lo0 = odd ? (alo[2] + blo[2]) : (alo[0] + blo[0]);
        float hi0 = odd ? (ahc[1] + bhc[1]) : (ap3 + bp3);
        // k = 2ug+1: lo elem e0+1 ; hi u=k-1=2ug: elem e0
        float lo1 = odd ? (alo[3] + blo[3]) : (alo[1] + blo[1]);
        float hi1 = odd ? (ahc[2] + bhc[2]) : (ahc[0] + bhc[0]);

        o0[s] = lo0 + hi0;
        o1[s] = lo1 + hi1;
        tl[s] = ahc[3] + bhc[3];   // u = 63 contribution (ug==31 only)
    }

    long orow = ((long)(bc * H_OUT) + (4 * ip + r)) * H_OUT;  // multiple of 4
    vfloat4* op = (vfloat4*)(out + orow);
    op[2 * ug + 0] = o0;
    op[2 * ug + 1] = o1;
    if (ug == 31) {
        op[64] = tl;               // w = 256..259
    }

    // ---- extra row ip=64 (h = 256+r): hi kernel row only, H==7 blocks ----
    if (H == 7 && t < 65) {
        int u = t;                 // output float4 index
        const float* pb = x + ((long)(bc * 64 + (r + 4) * 8)) * L + 63 * 64;
        vfloat4 v;
        #pragma unroll
        for (int s = 0; s < 4; ++s) {
            float lo = (u <= 63) ? pb[(long)s * L + u] : 0.f;
            float hi = (u >= 1) ? pb[(long)(s + 4) * L + u - 1] : 0.f;
            v[s] = lo + hi;
        }
        ((vfloat4*)(out + ((long)(bc * H_OUT) + 256 + r) * H_OUT))[u] = v;
    }
}

extern "C" void kernel_launch(void* const* d_in, const int* in_sizes, int n_in,
                              void* d_out, int out_size, void* d_ws, size_t ws_size,
                              hipStream_t stream) {
    const float* x = (const float*)d_in[0];
    float* out     = (float*)d_out;

    // blocks = 256 bc * 4 r * 8 H = 8192, 256 threads, 32 KB LDS each.
    fold_kernel<<<8192, 256, 0, stream>>>(x, out);
}